// Round 1
// baseline (188.740 us; speedup 1.0000x reference)
//
#include <hip/hip_runtime.h>
#include <math.h>

// Problem geometry: seg_out/logits (2,4,128,128,128) f32, y (2,1,128,128,128) i32,
// calib (20,4) f32, weight scalar int. Output: 1 f32 scalar.
#define VB 2097152            // voxels per (batch, channel) = 128^3
#define QB (VB / 4)           // float4 quads per (batch, channel)
#define NBINS 20

// Workspace layout (as 32-bit words):
//   [0..39]    float acc[2][5][4]  : b, quantity {Sp, Spt1, Cnt1, St2, Spt2}, channel
//   [40..119]  uint  bins[2][2][20]: class-1 (c=1,2), kind {true, total}, bin
#define WS_WORDS 120

__device__ __forceinline__ float sel(const float4 v, int j) {
    return j == 0 ? v.x : (j == 1 ? v.y : (j == 2 ? v.z : v.w));
}
__device__ __forceinline__ int seli(const int4 v, int j) {
    return j == 0 ? v.x : (j == 1 ? v.y : (j == 2 ? v.z : v.w));
}

__global__ void zero_ws_k(float* __restrict__ ws) {
    int i = blockIdx.x * blockDim.x + threadIdx.x;
    if (i < WS_WORDS) ws[i] = 0.0f;   // zero bits also zero the uint region
}

__global__ __launch_bounds__(256) void hybrid_main_k(
        const float* __restrict__ seg, const float* __restrict__ logits,
        const int* __restrict__ y, const int* __restrict__ wt,
        float* __restrict__ ws)
{
    const int b   = blockIdx.x & 1;       // interleave batches across XCDs
    const int blk = blockIdx.x >> 1;      // 0..511
    const int tid = threadIdx.x;

    __shared__ unsigned int shb[80];      // [cc][kind][bin] flat: cc*40 + kind*20 + bin
    __shared__ float shred[20][4];

    for (int i = tid; i < 80; i += 256) shb[i] = 0u;
    __syncthreads();

    // weight==1 => (1-w)*L2 == 0 exactly; skip the logits stream (uniform branch,
    // deterministic across calls since inputs are restored each launch).
    const bool need2 = (wt[0] != 1);

    const float4* s0 = (const float4*)seg + (size_t)(b * 4 + 0) * QB;
    const float4* s1 = (const float4*)seg + (size_t)(b * 4 + 1) * QB;
    const float4* s2 = (const float4*)seg + (size_t)(b * 4 + 2) * QB;
    const float4* s3 = (const float4*)seg + (size_t)(b * 4 + 3) * QB;
    const float4* l0 = (const float4*)logits + (size_t)(b * 4 + 0) * QB;
    const float4* l1 = (const float4*)logits + (size_t)(b * 4 + 1) * QB;
    const float4* l2 = (const float4*)logits + (size_t)(b * 4 + 2) * QB;
    const float4* l3 = (const float4*)logits + (size_t)(b * 4 + 3) * QB;
    const int4*   yq = (const int4*)y + (size_t)b * QB;

    // acc[0..3]=Sp, [4..7]=Spt1(one-hot), [8..11]=Cnt1(as float, exact<2^24),
    // [12..15]=St2(sigmoid), [16..19]=Spt2
    float acc[20];
    #pragma unroll
    for (int k = 0; k < 20; ++k) acc[k] = 0.0f;

    const float INV_STEP = 20.0f / (1.0f + 1e-8f);  // searchsorted(linspace(0,1+1e-8,21),'right')-1

    for (int q = blk * 256 + tid; q < QB; q += 512 * 256) {
        const int4   yv = yq[q];
        const float4 p0 = s0[q], p1 = s1[q], p2 = s2[q], p3 = s3[q];
        float4 g0 = {0,0,0,0}, g1 = {0,0,0,0}, g2 = {0,0,0,0}, g3 = {0,0,0,0};
        if (need2) { g0 = l0[q]; g1 = l1[q]; g2 = l2[q]; g3 = l3[q]; }

        #pragma unroll
        for (int j = 0; j < 4; ++j) {
            const float pv0 = sel(p0, j), pv1 = sel(p1, j), pv2 = sel(p2, j), pv3 = sel(p3, j);
            const int yj = seli(yv, j);

            acc[0] += pv0; acc[1] += pv1; acc[2] += pv2; acc[3] += pv3;
            acc[4] += (yj == 0) ? pv0 : 0.0f;
            acc[5] += (yj == 1) ? pv1 : 0.0f;
            acc[6] += (yj == 2) ? pv2 : 0.0f;
            acc[7] += (yj == 3) ? pv3 : 0.0f;
            acc[8]  += (yj == 0) ? 1.0f : 0.0f;
            acc[9]  += (yj == 1) ? 1.0f : 0.0f;
            acc[10] += (yj == 2) ? 1.0f : 0.0f;
            acc[11] += (yj == 3) ? 1.0f : 0.0f;

            if (need2) {
                const float gv0 = sel(g0, j), gv1 = sel(g1, j), gv2 = sel(g2, j), gv3 = sel(g3, j);
                const float sg0 = __fdividef(1.0f, 1.0f + __expf(-gv0));
                const float sg1 = __fdividef(1.0f, 1.0f + __expf(-gv1));
                const float sg2 = __fdividef(1.0f, 1.0f + __expf(-gv2));
                const float sg3 = __fdividef(1.0f, 1.0f + __expf(-gv3));
                acc[12] += sg0; acc[13] += sg1; acc[14] += sg2; acc[15] += sg3;
                acc[16] += pv0 * sg0; acc[17] += pv1 * sg1;
                acc[18] += pv2 * sg2; acc[19] += pv3 * sg3;
            }

            // softmax over channels (matches jax.nn.softmax: exp(x - max)/sum)
            const float mx = fmaxf(fmaxf(pv0, pv1), fmaxf(pv2, pv3));
            const float e0 = __expf(pv0 - mx), e1 = __expf(pv1 - mx);
            const float e2 = __expf(pv2 - mx), e3 = __expf(pv3 - mx);
            const float ssum = (e0 + e1) + (e2 + e3);
            const float pr1 = __fdividef(e1, ssum);
            const float pr2 = __fdividef(e2, ssum);
            int b1 = (int)(pr1 * INV_STEP); if (b1 > 19) b1 = 19;
            int b2 = (int)(pr2 * INV_STEP); if (b2 > 19) b2 = 19;
            atomicAdd(&shb[20 + b1], 1u);              // cc=0 (class 1) total
            atomicAdd(&shb[60 + b2], 1u);              // cc=1 (class 2) total
            if (yj == 1) atomicAdd(&shb[0 + b1], 1u);  // cc=0 true
            if (yj == 2) atomicAdd(&shb[40 + b2], 1u); // cc=1 true
        }
    }

    // wave(64) shuffle reduce each of the 20 accumulators
    #pragma unroll
    for (int k = 0; k < 20; ++k) {
        float v = acc[k];
        #pragma unroll
        for (int off = 32; off > 0; off >>= 1) v += __shfl_xor(v, off, 64);
        acc[k] = v;
    }
    const int wave = tid >> 6, lane = tid & 63;
    if (lane == 0) {
        #pragma unroll
        for (int k = 0; k < 20; ++k) shred[k][wave] = acc[k];
    }
    __syncthreads();
    if (tid < 20) {
        float t = shred[tid][0] + shred[tid][1] + shred[tid][2] + shred[tid][3];
        atomicAdd(&ws[b * 20 + tid], t);
    }
    if (tid < 80) {
        unsigned int v = shb[tid];
        if (v) atomicAdd((unsigned int*)ws + 40 + tid, v);
    }
}

__device__ __forceinline__ double dsigmoid(double x) { return 1.0 / (1.0 + exp(-x)); }

__device__ double dice_term(const double Sp[2], const double St[2], const double Spt[2],
                            double w0, double w1)
{
    const double sumP = Sp[0] + Sp[1], sumT = St[0] + St[1];
    const double u1 = sumP + sumT;
    const double u0 = (2.0 * (double)VB - sumP) + (2.0 * (double)VB - sumT);
    const double uni = w0 * u0 + w1 * u1;
    double dsum = 0.0;
    for (int b = 0; b < 2; ++b) {
        const double i1 = Spt[b];
        const double i0 = (double)VB - Sp[b] - St[b] + Spt[b];
        const double inter = w0 * i0 + w1 * i1;
        double dice = (2.0 * inter + 1.0) / (uni + 1.0);
        if (isnan(dice)) dice = 1.0;
        dsum += dice;
    }
    return 1.0 - 0.5 * dsum;
}

__global__ void finalize_k(const float* __restrict__ ws,
                           const float* __restrict__ calib,
                           const int* __restrict__ wt,
                           float* __restrict__ out)
{
    if (threadIdx.x != 0 || blockIdx.x != 0) return;
    const double means[4] = {0.03, 0.02, 0.01, 0.01};
    double L1 = 0.0, L2 = 0.0;
    for (int c = 0; c < 4; ++c) {
        const double mean = means[c];
        const double w1 = 1.0 / (mean * mean);
        const double w0 = 1.0 / ((1.0 - mean) * (1.0 - mean));
        double Sp[2], Spt1[2], C1[2], St2[2], Spt2[2];
        for (int b = 0; b < 2; ++b) {
            Sp[b]   = (double)ws[b * 20 + 0 + c];
            Spt1[b] = (double)ws[b * 20 + 4 + c];
            C1[b]   = (double)ws[b * 20 + 8 + c];
            St2[b]  = (double)ws[b * 20 + 12 + c];
            Spt2[b] = (double)ws[b * 20 + 16 + c];
        }
        L1 += dice_term(Sp, C1, Spt1, w0, w1);
        L2 += dice_term(Sp, St2, Spt2, w0, w1);
    }
    L1 *= 0.2; L2 *= 0.2;   // sum of 4 channel losses / 5.0

    const unsigned int* bins = (const unsigned int*)ws + 40;
    double ece = 0.0;
    for (int cc = 0; cc < 2; ++cc) {        // classes 1 and 2
        const int cls = cc + 1;
        double s = 0.0;
        for (int k = 0; k < NBINS; ++k) {
            const double bt   = dsigmoid((double)bins[cc * 40 + k]);
            const double btot = dsigmoid((double)bins[cc * 40 + 20 + k]);
            const double cal  = dsigmoid((double)calib[k * 4 + cls]);
            const double d = cal - bt / btot;
            s += d * d;
        }
        ece += s / (double)NBINS;
    }
    const double w = (double)wt[0];
    out[0] = (float)(w * L1 + (1.0 - w) * L2 + ece);
}

extern "C" void kernel_launch(void* const* d_in, const int* in_sizes, int n_in,
                              void* d_out, int out_size, void* d_ws, size_t ws_size,
                              hipStream_t stream)
{
    const float* seg    = (const float*)d_in[0];
    const float* calib  = (const float*)d_in[1];
    const float* logits = (const float*)d_in[2];
    const int*   y      = (const int*)d_in[3];
    const int*   wt     = (const int*)d_in[4];
    float* ws  = (float*)d_ws;
    float* out = (float*)d_out;

    hipLaunchKernelGGL(zero_ws_k, dim3(1), dim3(128), 0, stream, ws);
    hipLaunchKernelGGL(hybrid_main_k, dim3(1024), dim3(256), 0, stream,
                       seg, logits, y, wt, ws);
    hipLaunchKernelGGL(finalize_k, dim3(1), dim3(64), 0, stream, ws, calib, wt, out);
}